// Round 5
// baseline (275.943 us; speedup 1.0000x reference)
//
#include <hip/hip_runtime.h>
#include <hip/hip_bf16.h>

// Attention forward, MI355X (gfx950). fp32 in/out, bf16 MFMA internally.
// ws (56 MB): wqkv_b[3072x1024 bf16] | wo_b[1024x1024 bf16] | QKV[8192x3072 bf16]
// xb (bf16 x) lives in d_out's first 16 MB (dead before out-proj writes).
// Dispatches: 1 fused convert; QKV GEMM; flash; out-proj GEMM.
// MFMA layouts (verified m89/m74):
//   A-frag: A[m=lane&15][k=(lane>>4)*8+j]; B-frag: B[n=lane&15][k=...]
//   C/D:    col=lane&15, row=(lane>>4)*4+reg
//
// Round-8:  both-sides LDS swizzles in flash. Conflicts 1.62e7->6.5e6, dur flat.
// Round-9:  lgkm-only barrier in flash. 163->157 us.
// Round-10: K LDS-staged (pre-swizzled source) + XCD grouping in flash.
//           FETCH 240->38 MB, flash 157->89.6 us. Latency theory confirmed.
// Round-11: GEMM XCD remap + BK=64 swizzled staging + fused converts.
//           Total 280.8->262.3; flash unchanged (88.6).
// Round-12 (this): FUSED flash passes. One p-loop serves both q-tiles of the
//   pair (m, 31-m): K LDS-reads shared, barriers/staging 33->32-m per block
//   (avg 24.5), MFMA-iters still exactly 33/block. Per-CU balance via pk
//   interleave decode (4 consecutive same-XCD blocks sum np=98) which also
//   makes same-CU blocks share the (b,head) K/V panel.

typedef short short8 __attribute__((ext_vector_type(8)));
typedef float f32x4 __attribute__((ext_vector_type(4)));

#define MFMA16(a, b, c) __builtin_amdgcn_mfma_f32_16x16x32_bf16((a), (b), (c), 0, 0, 0)

static __device__ __forceinline__ ushort f2bf(float f) {
  union { __hip_bfloat16 h; ushort u; } cv;
  cv.h = __float2bfloat16(f);
  return cv.u;
}

static __device__ __forceinline__ float fexp2(float x) {
#if __has_builtin(__builtin_amdgcn_exp2f)
  return __builtin_amdgcn_exp2f(x);
#else
  return __expf(x * 0.69314718056f);
#endif
}

// Barrier WITHOUT any vmcnt drain: LDS writes visible, globals keep flying.
static __device__ __forceinline__ void block_sync_lds() {
  asm volatile("s_waitcnt lgkmcnt(0)" ::: "memory");
  __builtin_amdgcn_s_barrier();
  __builtin_amdgcn_sched_barrier(0);
}

// Barrier that ALSO waits outstanding globals (global_load_lds visibility).
static __device__ __forceinline__ void block_sync_full() {
  asm volatile("s_waitcnt vmcnt(0) lgkmcnt(0)" ::: "memory");
  __builtin_amdgcn_s_barrier();
  __builtin_amdgcn_sched_barrier(0);
}

static __device__ __forceinline__ void store_out(float* p, float v) { *p = v; }
static __device__ __forceinline__ void store_out(__hip_bfloat16* p, float v) {
  *p = __float2bfloat16(v);
}

// One fused convert: wq|wk|wv -> wqkv_b rows, wo -> wo_b, x -> xb.
__global__ __launch_bounds__(256) void convert_all_kernel(
    const float* __restrict__ wq, const float* __restrict__ wk,
    const float* __restrict__ wv, const float* __restrict__ wo,
    const float* __restrict__ x, ushort* __restrict__ wqkv,
    ushort* __restrict__ wob, ushort* __restrict__ xb) {
  constexpr int W4 = 262144;           // (1024*1024)/4
  constexpr size_t WSZ = (size_t)1024 * 1024;
  const int i = blockIdx.x * blockDim.x + threadIdx.x;
  const float* src;
  ushort* dst;
  int j;
  if (i < 2 * W4) {
    if (i < W4)      { src = wq; dst = wqkv;           j = i; }
    else             { src = wk; dst = wqkv + WSZ;     j = i - W4; }
  } else if (i < 4 * W4) {
    if (i < 3 * W4)  { src = wv; dst = wqkv + 2 * WSZ; j = i - 2 * W4; }
    else             { src = wo; dst = wob;            j = i - 3 * W4; }
  } else {
    src = x; dst = xb; j = i - 4 * W4;
  }
  const float4 v = ((const float4*)src)[j];
  ushort4 o;
  o.x = f2bf(v.x); o.y = f2bf(v.y); o.z = f2bf(v.z); o.w = f2bf(v.w);
  ((ushort4*)dst)[j] = o;
}

// C[M,N] = A[M,K](bf16) * B[N,K]^T(bf16), fp32 acc. 128x128 block tile,
// BK=64, both operands staged via global_load_lds width 16 with PRE-SWIZZLED
// SOURCE (rule 21): fragment ds_read_b128 conflict-free. 4 waves, 64x64/wave.
// XCD remap: id&7 = XCD owns N-tile chunk of size cpx.
template <typename OUT_T>
__global__ __launch_bounds__(256) void gemm_kernel(
    const ushort* __restrict__ A, int lda, const ushort* __restrict__ B, int ldb,
    OUT_T* __restrict__ C, int ldc, int K, int cpx) {
  __shared__ __align__(16) ushort As[128 * 64];
  __shared__ __align__(16) ushort Bs[128 * 64];
  const int tid = threadIdx.x;
  const int wave = tid >> 6, lane = tid & 63;
  const int lm = lane & 15, quad = lane >> 4;

  const int id = blockIdx.x;
  const int local = id >> 3;
  const int nt = (id & 7) * cpx + local % cpx;
  const int mt = local / cpx;
  const size_t m0 = (size_t)mt * 128;
  const size_t n0 = (size_t)nt * 128;

  const int rl = lane >> 3;        // row within 8-row staging chunk
  const int cs = (lane & 7) ^ rl;  // pre-swizzled source col-chunk
  const int fsw = lm & 7;          // fragment read swizzle key

  f32x4 acc[4][4] = {};
  for (int k0 = 0; k0 < K; k0 += 64) {
    __syncthreads();
#pragma unroll
    for (int j = 0; j < 4; ++j) {
      const int ch = wave * 4 + j;  // 8-row chunk 0..15
      const ushort* gb = B + (n0 + ch * 8 + rl) * (size_t)ldb + k0 + cs * 8;
      __builtin_amdgcn_global_load_lds(
          (const __attribute__((address_space(1))) void*)gb,
          (__attribute__((address_space(3))) void*)(Bs + ch * 512), 16, 0, 0);
      const ushort* ga = A + (m0 + ch * 8 + rl) * (size_t)lda + k0 + cs * 8;
      __builtin_amdgcn_global_load_lds(
          (const __attribute__((address_space(1))) void*)ga,
          (__attribute__((address_space(3))) void*)(As + ch * 512), 16, 0, 0);
    }
    __syncthreads();  // vmcnt drain required: staging must be visible

    const int wm = (wave >> 1) * 64, wn = (wave & 1) * 64;
#pragma unroll
    for (int ks = 0; ks < 2; ++ks) {
      short8 a[4], b[4];
#pragma unroll
      for (int i = 0; i < 4; ++i)
        a[i] = *(const short8*)(As + (wm + i * 16 + lm) * 64 +
                                ((((ks * 4 + quad) ^ fsw) & 7) << 3));
#pragma unroll
      for (int j = 0; j < 4; ++j)
        b[j] = *(const short8*)(Bs + (wn + j * 16 + lm) * 64 +
                                ((((ks * 4 + quad) ^ fsw) & 7) << 3));
#pragma unroll
      for (int i = 0; i < 4; ++i)
#pragma unroll
        for (int j = 0; j < 4; ++j)
          acc[i][j] = MFMA16(a[i], b[j], acc[i][j]);
    }
  }

  const int wm = (wave >> 1) * 64, wn = (wave & 1) * 64;
  const int rq = quad * 4;
#pragma unroll
  for (int i = 0; i < 4; ++i)
#pragma unroll
    for (int j = 0; j < 4; ++j)
#pragma unroll
      for (int r = 0; r < 4; ++r)
        store_out(&C[(m0 + wm + i * 16 + rq + r) * (size_t)ldc + n0 + wn + j * 16 + lm],
                  acc[i][j][r]);
}

// Swizzled V^T LDS write: 8 cols starting at h0 for row p.
// Element (p, h) lives at h*64 + (((p>>3) ^ (h>>3) ^ (h&7)) & 7)*8 + (p&7).
static __device__ __forceinline__ void vt_write8(ushort* vtbuf, int h0, int hsw,
                                                 int p, const short8& v) {
  const int pc = (p >> 3) ^ hsw;
  ushort* row = vtbuf + h0 * 64 + (p & 7);
#pragma unroll
  for (int u = 0; u < 8; ++u)
    row[u * 64 + (((pc ^ u) & 7) << 3)] = ((const ushort*)&v)[u];
}

// Stage a 64x64 bf16 K tile (global rows pbase..pbase+63) into kbuf via
// global_load_lds, pre-swizzled source (rule 21).
static __device__ __forceinline__ void stage_k(const ushort* kglob, int pbase,
                                               ushort* kbuf, int wave, int lane) {
  const int rl = lane >> 3;           // row within the 8-row chunk (== r&7)
  const int c = (lane & 7) ^ rl;      // inverse-swizzled source chunk
#pragma unroll
  for (int j = 0; j < 2; ++j) {
    const int ch = wave * 2 + j;
    const ushort* src = kglob + (size_t)(pbase + ch * 8 + rl) * 3072 + c * 8;
    __builtin_amdgcn_global_load_lds(
        (const __attribute__((address_space(1))) void*)src,
        (__attribute__((address_space(3))) void*)(kbuf + ch * 512), 16, 0, 0);
  }
}

// Flash causal attention, FUSED pair loop. QKV[8192][3072]: Q cols 0..1023,
// K 1024..2047, V 2048..3071; head h at sub-col h*64. Z over Q in-place.
// Block decode (flat 1024): xcd=id&7, pk=(id>>3)&15, gq=id>>7.
//   g = xcd*8+gq (b,head group, XCD-local); m = (pk&1)? 15-(pk>>1) : pk>>1.
// Block owns q-tiles A=m, B=31-m; ONE p-loop it=0..31-m (np=32-m iters):
//   tile B active all iters (diag at last), tile A active it<=m (diag at m).
//   K LDS fragments read once per iter, feed both tiles' QK^T.
//   MFMA-iters = (m+1)+(32-m) = 33 per block (balanced); np varies 17..32
//   but any 4 consecutive same-XCD blocks (one CU's residency) sum np=98
//   and share the group's K/V panel.
// Block = 4 waves; wave = 16 q-rows/tile. S^T = K*Q^T: lane owns q-row +lm.
// Fixed-shift softmax: p = exp2(S*log2e/8). K: double-buffered LDS via
// pre-swizzled-source global_load_lds. V^T: double-buffered LDS (xor-swizzled
// both sides). P: per-wave LDS region, reused A-then-B (same-wave DS order).
__global__ __launch_bounds__(256) void flash4_kernel(ushort* __restrict__ QKV) {
  constexpr int LD = 3072;
  __shared__ __align__(16) ushort vt[2][64 * 64];
  __shared__ __align__(16) ushort kt[2][64 * 64];
  __shared__ __align__(16) ushort pbuf[4][16 * 64];

  const int id = blockIdx.x;
  const int pk = (id >> 3) & 15;
  const int g = (id & 7) * 8 + (id >> 7);        // (b,head) group, XCD-local
  const int m = (pk & 1) ? 15 - (pk >> 1) : (pk >> 1);
  const int head = g & 15;
  const int b = g >> 4;

  const int tid = threadIdx.x;
  const int wave = tid >> 6, lane = tid & 63;
  const int lm = lane & 15, quad = lane >> 4;

  const size_t qcol = (size_t)b * 2048 * LD + head * 64;
  const size_t vcol = qcol + 2048;
  const ushort* kglob = QKV + qcol + 1024;

  const int h0 = (tid & 7) * 8;  // V staging: 8 cols per thread
  const int hsw = tid & 7;
  const int plb = tid >> 3;      // V staging p base (0..31)
  const int psw = lm & 7;        // pbuf row swizzle key
  const int ksw = lm & 7;        // kt fragment swizzle key

  constexpr float CSC = 0.180336880f;  // log2(e)/8

  const int qrowA = m * 64 + wave * 16;
  const int qrowB = (31 - m) * 64 + wave * 16;
  const int qgA = qrowA + lm;
  const int qgB = qrowB + lm;
  const int np = 32 - m;

  // Q fragments for both tiles (held in registers for the whole loop)
  const ushort* qpA = QKV + qcol + (size_t)(qrowA + lm) * LD;
  short8 qaA0 = *(const short8*)(qpA + quad * 8);
  short8 qaA1 = *(const short8*)(qpA + 32 + quad * 8);
  const ushort* qpB = QKV + qcol + (size_t)(qrowB + lm) * LD;
  short8 qaB0 = *(const short8*)(qpB + quad * 8);
  short8 qaB1 = *(const short8*)(qpB + 32 + quad * 8);

  f32x4 acczA[4] = {}, acczB[4] = {};
  float llA = 0.f, llB = 0.f;

  // prologue: K tile 0 -> kt[0] (direct-to-LDS), V tile 0 -> vt[0]
  stage_k(kglob, 0, kt[0], wave, lane);
#pragma unroll
  for (int rr = 0; rr < 2; ++rr) {
    const int p = plb + rr * 32;
    short8 v = *(const short8*)(QKV + vcol + (size_t)p * LD + h0);
    vt_write8(vt[0], h0, hsw, p, v);
  }

  for (int it = 0; it < np; ++it) {
    const int p0 = it * 64;
    // kt/vt of this iter visible; only well-aged stage loads drained.
    block_sync_full();

    // K fragments from LDS (block-shared; swizzled chunks, conflict-free)
    short8 ka[4], kb[4];
    const ushort* kbuf = kt[it & 1];
#pragma unroll
    for (int s = 0; s < 4; ++s) {
      const ushort* kr = kbuf + (s * 16 + lm) * 64;
      ka[s] = *(const short8*)(kr + (((quad ^ ksw) & 7) << 3));
      kb[s] = *(const short8*)(kr + ((((quad + 4) ^ ksw) & 7) << 3));
    }

    const bool more = (it + 1 < np);
    short8 nv0, nv1;
    if (more) {
      nv0 = *(const short8*)(QKV + vcol + (size_t)(p0 + 64 + plb) * LD + h0);
      nv1 = *(const short8*)(QKV + vcol + (size_t)(p0 + 96 + plb) * LD + h0);
      stage_k(kglob, p0 + 64, kt[(it + 1) & 1], wave, lane);
    }

    const bool actA = (it <= m);

    // scores S^T[p][q]: tile A first (if active), then B — A's results land
    // first so its softmax overlaps B's MFMAs.
    f32x4 t4A[4], t4B[4];
    if (actA) {
#pragma unroll
      for (int s = 0; s < 4; ++s) {
        f32x4 t = {0.f, 0.f, 0.f, 0.f};
        t = MFMA16(ka[s], qaA0, t);
        t = MFMA16(kb[s], qaA1, t);
        t4A[s] = t;
      }
    }
#pragma unroll
    for (int s = 0; s < 4; ++s) {
      f32x4 t = {0.f, 0.f, 0.f, 0.f};
      t = MFMA16(ka[s], qaB0, t);
      t = MFMA16(kb[s], qaB1, t);
      t4B[s] = t;
    }

    const ushort* vbuf = vt[it & 1];
    ushort* pw = pbuf[wave] + lm * 64;

    // ---- tile A: softmax, pack, PV (pbuf region reused by B afterwards;
    // same-wave DS program order guarantees read-before-overwrite) ----
    if (actA) {
      float ps[4][4];
      if (it != m) {
#pragma unroll
        for (int s = 0; s < 4; ++s) {
#pragma unroll
          for (int r = 0; r < 4; ++r)
            ps[s][r] = fexp2(t4A[s][r] * CSC);
          llA += (ps[s][0] + ps[s][1]) + (ps[s][2] + ps[s][3]);
        }
      } else {
#pragma unroll
        for (int s = 0; s < 4; ++s) {
#pragma unroll
          for (int r = 0; r < 4; ++r) {
            const int pg = p0 + s * 16 + quad * 4 + r;
            const float e = fexp2(t4A[s][r] * CSC);
            ps[s][r] = (pg > qgA) ? 0.f : e;
          }
          llA += (ps[s][0] + ps[s][1]) + (ps[s][2] + ps[s][3]);
        }
      }
#pragma unroll
      for (int s = 0; s < 4; ++s) {
        uint2 pkv;
        pkv.x = (uint)f2bf(ps[s][0]) | ((uint)f2bf(ps[s][1]) << 16);
        pkv.y = (uint)f2bf(ps[s][2]) | ((uint)f2bf(ps[s][3]) << 16);
        *(uint2*)(pw + ((((2 * s + (quad >> 1)) ^ psw) & 7) << 3) +
                  ((quad & 1) << 2)) = pkv;
      }
#pragma unroll
      for (int kc = 0; kc < 2; ++kc) {
        short8 pa = *(const short8*)(pw + ((((kc * 4 + quad) ^ psw) & 7) << 3));
#pragma unroll
        for (int c = 0; c < 4; ++c) {
          const int hrow = c * 16 + lm;
          const int fh = ((hrow >> 3) ^ hrow) & 7;
          short8 vb = *(const short8*)(
              vbuf + hrow * 64 + ((((4 * kc + quad) ^ fh) & 7) << 3));
          acczA[c] = MFMA16(pa, vb, acczA[c]);
        }
      }
    }

    // ---- tile B: softmax, pack, PV ----
    {
      float ps[4][4];
      if (it != np - 1) {
#pragma unroll
        for (int s = 0; s < 4; ++s) {
#pragma unroll
          for (int r = 0; r < 4; ++r)
            ps[s][r] = fexp2(t4B[s][r] * CSC);
          llB += (ps[s][0] + ps[s][1]) + (ps[s][2] + ps[s][3]);
        }
      } else {
#pragma unroll
        for (int s = 0; s < 4; ++s) {
#pragma unroll
          for (int r = 0; r < 4; ++r) {
            const int pg = p0 + s * 16 + quad * 4 + r;
            const float e = fexp2(t4B[s][r] * CSC);
            ps[s][r] = (pg > qgB) ? 0.f : e;
          }
          llB += (ps[s][0] + ps[s][1]) + (ps[s][2] + ps[s][3]);
        }
      }
#pragma unroll
      for (int s = 0; s < 4; ++s) {
        uint2 pkv;
        pkv.x = (uint)f2bf(ps[s][0]) | ((uint)f2bf(ps[s][1]) << 16);
        pkv.y = (uint)f2bf(ps[s][2]) | ((uint)f2bf(ps[s][3]) << 16);
        *(uint2*)(pw + ((((2 * s + (quad >> 1)) ^ psw) & 7) << 3) +
                  ((quad & 1) << 2)) = pkv;
      }
#pragma unroll
      for (int kc = 0; kc < 2; ++kc) {
        short8 pa = *(const short8*)(pw + ((((kc * 4 + quad) ^ psw) & 7) << 3));
#pragma unroll
        for (int c = 0; c < 4; ++c) {
          const int hrow = c * 16 + lm;
          const int fh = ((hrow >> 3) ^ hrow) & 7;
          short8 vb = *(const short8*)(
              vbuf + hrow * 64 + ((((4 * kc + quad) ^ fh) & 7) << 3));
          acczB[c] = MFMA16(pa, vb, acczB[c]);
        }
      }
    }

    // late LDS writes of next V tile (other buffer); vmcnt wait for nv0/nv1
    // is counted (stage_k loads stay outstanding until next barrier).
    if (more) {
      ushort* nbuf = vt[(it + 1) & 1];
      vt_write8(nbuf, h0, hsw, plb, nv0);
      vt_write8(nbuf, h0, hsw, plb + 32, nv1);
    }
  }

  // epilogue: row-sums via 2 shfl_xor per tile, then scale + write Z over Q
  {
    float lt = llA;
    lt += __shfl_xor(lt, 16, 64);
    lt += __shfl_xor(lt, 32, 64);
#pragma unroll
    for (int r = 0; r < 4; ++r) {
      const float lr = __shfl(lt, quad * 4 + r, 64);
      const float inv = 1.f / lr;
#pragma unroll
      for (int c = 0; c < 4; ++c)
        QKV[qcol + (size_t)(qrowA + quad * 4 + r) * LD + c * 16 + lm] =
            f2bf(acczA[c][r] * inv);
    }
  }
  {
    float lt = llB;
    lt += __shfl_xor(lt, 16, 64);
    lt += __shfl_xor(lt, 32, 64);
#pragma unroll
    for (int r = 0; r < 4; ++r) {
      const float lr = __shfl(lt, quad * 4 + r, 64);
      const float inv = 1.f / lr;
#pragma unroll
      for (int c = 0; c < 4; ++c)
        QKV[qcol + (size_t)(qrowB + quad * 4 + r) * LD + c * 16 + lm] =
            f2bf(acczB[c][r] * inv);
    }
  }
}

extern "C" void kernel_launch(void* const* d_in, const int* in_sizes, int n_in,
                              void* d_out, int out_size, void* d_ws, size_t ws_size,
                              hipStream_t stream) {
  (void)in_sizes; (void)n_in; (void)out_size; (void)ws_size;
  const float* x  = (const float*)d_in[0];   // (4,2048,1024) = (8192,1024)
  const float* wk = (const float*)d_in[1];   // (16,64,1024) flat (1024,1024)
  const float* wq = (const float*)d_in[2];
  const float* wv = (const float*)d_in[3];
  const float* wo = (const float*)d_in[4];   // (1024,1024)
  float* out = (float*)d_out;

  const size_t WSZ = (size_t)1024 * 1024;
  ushort* wqkv_b = (ushort*)d_ws;            // rows: 0..1023 Q, 1024.. K, 2048.. V
  ushort* wo_b = wqkv_b + 3 * WSZ;
  ushort* QKV = wo_b + WSZ;                  // 8192 x 3072
  ushort* xb = (ushort*)d_out;               // bf16 x in d_out (16 of 32 MB);
                                             // dead before out-proj writes

  // Fused converts: 4*(1M/4) + (8M/4) = 3145728 float4s = 12288 blocks exact.
  convert_all_kernel<<<12288, 256, 0, stream>>>(wq, wk, wv, wo, x,
                                                wqkv_b, wo_b, xb);

  // All-batch QKV projection. Grid 24 N-tiles x 64 M-tiles = 1536 blocks;
  // XCD remap cpx=3: each XCD's 768 KB B sub-panel stays L2-resident.
  gemm_kernel<__hip_bfloat16><<<1536, 256, 0, stream>>>(
      xb, 1024, wqkv_b, 1024, (__hip_bfloat16*)QKV, 3072, 1024, 3);

  flash4_kernel<<<1024, 256, 0, stream>>>(QKV);

  // Out projection: Z (QKV cols 0..1023) * Wo^T -> fp32 out.
  gemm_kernel<float><<<512, 256, 0, stream>>>(
      QKV, 3072, wo_b, 1024, out, 1024, 1024, 1);
}

// Round 6
// 264.625 us; speedup vs baseline: 1.0428x; 1.0428x over previous
//
#include <hip/hip_runtime.h>
#include <hip/hip_bf16.h>

// Attention forward, MI355X (gfx950). fp32 in/out, bf16 MFMA internally.
// ws (56 MB): wqkv_b[3072x1024 bf16] | wo_b[1024x1024 bf16] | QKV[8192x3072 bf16]
// xb (bf16 x) lives in d_out's first 16 MB (dead before out-proj writes).
// Dispatches: 1 fused convert; QKV GEMM; flash; out-proj GEMM.
// MFMA layouts (verified m89/m74):
//   A-frag: A[m=lane&15][k=(lane>>4)*8+j]; B-frag: B[n=lane&15][k=...]
//   C/D:    col=lane&15, row=(lane>>4)*4+reg
//
// Round-8:  both-sides LDS swizzles in flash. Conflicts 1.62e7->6.5e6, dur flat.
// Round-9:  lgkm-only barrier in flash. 163->157 us.
// Round-10: K LDS-staged (pre-swizzled source) + XCD grouping in flash.
//           FETCH 240->38 MB, flash 157->89.6 us. Latency theory confirmed.
// Round-11: GEMM XCD remap + BK=64 swizzled staging + fused converts.
//           Total 280.8->262.3; flash unchanged (88.6).
// Round-12: FUSED pair p-loop. FETCH 37.8->24.6 MB (K-sharing worked) BUT
//           flash 88.6->105.3: pk=(l&15) decode gave every CU 4 blocks of
//           IDENTICAL np (l mod 32 fixes l mod 16) -> 1.9x inter-CU imbalance,
//           occupancy 24.6->18. Lesson re-learned: np uniformity per block is
//           load-bearing; any variable-np scheme needs dispatch-proof balance.
// Round-13 (this): REVERT flash to round-4 structure (verified 88.6) + two
//   pipe-shift micros (VALU 44% busiest -> MFMA 16.6% idlest):
//   (a) l-sum via ones-MFMA: lacc = MFMA(pa, ones, lacc) per kc (2/iter)
//       replaces 12 VALU adds/iter AND the epilogue shfl reduce (C-layout
//       delivers per-q row sums in lacc[r] directly).
//   (b) T5 s_setprio(1) around QK^T and PV MFMA clusters (m191: +4-7% attn).

typedef short short8 __attribute__((ext_vector_type(8)));
typedef float f32x4 __attribute__((ext_vector_type(4)));

#define MFMA16(a, b, c) __builtin_amdgcn_mfma_f32_16x16x32_bf16((a), (b), (c), 0, 0, 0)

static __device__ __forceinline__ ushort f2bf(float f) {
  union { __hip_bfloat16 h; ushort u; } cv;
  cv.h = __float2bfloat16(f);
  return cv.u;
}

static __device__ __forceinline__ float fexp2(float x) {
#if __has_builtin(__builtin_amdgcn_exp2f)
  return __builtin_amdgcn_exp2f(x);
#else
  return __expf(x * 0.69314718056f);
#endif
}

// Barrier WITHOUT any vmcnt drain: LDS writes visible, globals keep flying.
static __device__ __forceinline__ void block_sync_lds() {
  asm volatile("s_waitcnt lgkmcnt(0)" ::: "memory");
  __builtin_amdgcn_s_barrier();
  __builtin_amdgcn_sched_barrier(0);
}

// Barrier that ALSO waits outstanding globals (global_load_lds visibility).
static __device__ __forceinline__ void block_sync_full() {
  asm volatile("s_waitcnt vmcnt(0) lgkmcnt(0)" ::: "memory");
  __builtin_amdgcn_s_barrier();
  __builtin_amdgcn_sched_barrier(0);
}

static __device__ __forceinline__ void store_out(float* p, float v) { *p = v; }
static __device__ __forceinline__ void store_out(__hip_bfloat16* p, float v) {
  *p = __float2bfloat16(v);
}

// One fused convert: wq|wk|wv -> wqkv_b rows, wo -> wo_b, x -> xb.
__global__ __launch_bounds__(256) void convert_all_kernel(
    const float* __restrict__ wq, const float* __restrict__ wk,
    const float* __restrict__ wv, const float* __restrict__ wo,
    const float* __restrict__ x, ushort* __restrict__ wqkv,
    ushort* __restrict__ wob, ushort* __restrict__ xb) {
  constexpr int W4 = 262144;           // (1024*1024)/4
  constexpr size_t WSZ = (size_t)1024 * 1024;
  const int i = blockIdx.x * blockDim.x + threadIdx.x;
  const float* src;
  ushort* dst;
  int j;
  if (i < 2 * W4) {
    if (i < W4)      { src = wq; dst = wqkv;           j = i; }
    else             { src = wk; dst = wqkv + WSZ;     j = i - W4; }
  } else if (i < 4 * W4) {
    if (i < 3 * W4)  { src = wv; dst = wqkv + 2 * WSZ; j = i - 2 * W4; }
    else             { src = wo; dst = wob;            j = i - 3 * W4; }
  } else {
    src = x; dst = xb; j = i - 4 * W4;
  }
  const float4 v = ((const float4*)src)[j];
  ushort4 o;
  o.x = f2bf(v.x); o.y = f2bf(v.y); o.z = f2bf(v.z); o.w = f2bf(v.w);
  ((ushort4*)dst)[j] = o;
}

// C[M,N] = A[M,K](bf16) * B[N,K]^T(bf16), fp32 acc. 128x128 block tile,
// BK=64, both operands staged via global_load_lds width 16 with PRE-SWIZZLED
// SOURCE (rule 21): fragment ds_read_b128 conflict-free. 4 waves, 64x64/wave.
// XCD remap: id&7 = XCD owns N-tile chunk of size cpx.
template <typename OUT_T>
__global__ __launch_bounds__(256) void gemm_kernel(
    const ushort* __restrict__ A, int lda, const ushort* __restrict__ B, int ldb,
    OUT_T* __restrict__ C, int ldc, int K, int cpx) {
  __shared__ __align__(16) ushort As[128 * 64];
  __shared__ __align__(16) ushort Bs[128 * 64];
  const int tid = threadIdx.x;
  const int wave = tid >> 6, lane = tid & 63;
  const int lm = lane & 15, quad = lane >> 4;

  const int id = blockIdx.x;
  const int local = id >> 3;
  const int nt = (id & 7) * cpx + local % cpx;
  const int mt = local / cpx;
  const size_t m0 = (size_t)mt * 128;
  const size_t n0 = (size_t)nt * 128;

  const int rl = lane >> 3;        // row within 8-row staging chunk
  const int cs = (lane & 7) ^ rl;  // pre-swizzled source col-chunk
  const int fsw = lm & 7;          // fragment read swizzle key

  f32x4 acc[4][4] = {};
  for (int k0 = 0; k0 < K; k0 += 64) {
    __syncthreads();
#pragma unroll
    for (int j = 0; j < 4; ++j) {
      const int ch = wave * 4 + j;  // 8-row chunk 0..15
      const ushort* gb = B + (n0 + ch * 8 + rl) * (size_t)ldb + k0 + cs * 8;
      __builtin_amdgcn_global_load_lds(
          (const __attribute__((address_space(1))) void*)gb,
          (__attribute__((address_space(3))) void*)(Bs + ch * 512), 16, 0, 0);
      const ushort* ga = A + (m0 + ch * 8 + rl) * (size_t)lda + k0 + cs * 8;
      __builtin_amdgcn_global_load_lds(
          (const __attribute__((address_space(1))) void*)ga,
          (__attribute__((address_space(3))) void*)(As + ch * 512), 16, 0, 0);
    }
    __syncthreads();  // vmcnt drain required: staging must be visible

    const int wm = (wave >> 1) * 64, wn = (wave & 1) * 64;
#pragma unroll
    for (int ks = 0; ks < 2; ++ks) {
      short8 a[4], b[4];
#pragma unroll
      for (int i = 0; i < 4; ++i)
        a[i] = *(const short8*)(As + (wm + i * 16 + lm) * 64 +
                                ((((ks * 4 + quad) ^ fsw) & 7) << 3));
#pragma unroll
      for (int j = 0; j < 4; ++j)
        b[j] = *(const short8*)(Bs + (wn + j * 16 + lm) * 64 +
                                ((((ks * 4 + quad) ^ fsw) & 7) << 3));
#pragma unroll
      for (int i = 0; i < 4; ++i)
#pragma unroll
        for (int j = 0; j < 4; ++j)
          acc[i][j] = MFMA16(a[i], b[j], acc[i][j]);
    }
  }

  const int wm = (wave >> 1) * 64, wn = (wave & 1) * 64;
  const int rq = quad * 4;
#pragma unroll
  for (int i = 0; i < 4; ++i)
#pragma unroll
    for (int j = 0; j < 4; ++j)
#pragma unroll
      for (int r = 0; r < 4; ++r)
        store_out(&C[(m0 + wm + i * 16 + rq + r) * (size_t)ldc + n0 + wn + j * 16 + lm],
                  acc[i][j][r]);
}

// Swizzled V^T LDS write: 8 cols starting at h0 for row p.
// Element (p, h) lives at h*64 + (((p>>3) ^ (h>>3) ^ (h&7)) & 7)*8 + (p&7).
static __device__ __forceinline__ void vt_write8(ushort* vtbuf, int h0, int hsw,
                                                 int p, const short8& v) {
  const int pc = (p >> 3) ^ hsw;
  ushort* row = vtbuf + h0 * 64 + (p & 7);
#pragma unroll
  for (int u = 0; u < 8; ++u)
    row[u * 64 + (((pc ^ u) & 7) << 3)] = ((const ushort*)&v)[u];
}

// Stage a 64x64 bf16 K tile (global rows pbase..pbase+63) into kbuf via
// global_load_lds, pre-swizzled source (rule 21).
static __device__ __forceinline__ void stage_k(const ushort* kglob, int pbase,
                                               ushort* kbuf, int wave, int lane) {
  const int rl = lane >> 3;           // row within the 8-row chunk (== r&7)
  const int c = (lane & 7) ^ rl;      // inverse-swizzled source chunk
#pragma unroll
  for (int j = 0; j < 2; ++j) {
    const int ch = wave * 2 + j;
    const ushort* src = kglob + (size_t)(pbase + ch * 8 + rl) * 3072 + c * 8;
    __builtin_amdgcn_global_load_lds(
        (const __attribute__((address_space(1))) void*)src,
        (__attribute__((address_space(3))) void*)(kbuf + ch * 512), 16, 0, 0);
  }
}

// Flash causal attention (round-4 structure, verified 88.6 us).
// QKV[8192][3072]: Q cols 0..1023, K 1024..2047, V 2048..3071; head h at
// sub-col h*64; row = b*2048 + pos. Z over Q in-place.
// Flat grid 1024, XCD-remapped: id&7 = xcd slot; all 16 q-pair blocks of one
// (b,head) group land on one XCD (8 groups/XCD) so K/V stay L2-resident.
// Each block runs q-tile pair (m, 31-m) sequentially -> exactly 33 p-tile
// iters per block: UNIFORM np (round-12 lesson: this is load-bearing).
// Block = 4 waves; wave = 16 q-rows. S^T = K*Q^T: lane owns q-row qrow+lm.
// Fixed-shift softmax: p = exp2(S*log2e/8) (exact; scores bounded ~10).
// l computed via ones-MFMA in PV (no VALU adds, no epilogue shuffles).
// K: block-shared LDS, double-buffered, pre-swizzled-source global_load_lds.
// V^T: double-buffered LDS (xor-swizzled both sides). P: per-wave LDS.
__global__ __launch_bounds__(256) void flash4_kernel(ushort* __restrict__ QKV) {
  constexpr int LD = 3072;
  __shared__ __align__(16) ushort vt[2][64 * 64];
  __shared__ __align__(16) ushort kt[2][64 * 64];
  __shared__ __align__(16) ushort pbuf[4][16 * 64];

  const int id = blockIdx.x;
  const int g = (id & 7) * 8 + ((id >> 3) & 7);  // (b,head) group, XCD-local
  const int m = id >> 6;                          // q-pair index 0..15
  const int head = g & 15;
  const int b = g >> 4;

  const int tid = threadIdx.x;
  const int wave = tid >> 6, lane = tid & 63;
  const int lm = lane & 15, quad = lane >> 4;

  const size_t qcol = (size_t)b * 2048 * LD + head * 64;
  const size_t vcol = qcol + 2048;
  const ushort* kglob = QKV + qcol + 1024;

  const int h0 = (tid & 7) * 8;  // V staging: 8 cols per thread
  const int hsw = tid & 7;
  const int plb = tid >> 3;      // V staging p base (0..31)
  const int psw = lm & 7;        // pbuf row swizzle key
  const int ksw = lm & 7;        // kt fragment swizzle key

  constexpr float CSC = 0.180336880f;  // log2(e)/8
  const short8 vone = {0x3F80, 0x3F80, 0x3F80, 0x3F80,
                       0x3F80, 0x3F80, 0x3F80, 0x3F80};  // bf16 1.0 x8

  for (int pass = 0; pass < 2; ++pass) {
    const int qbi = pass ? 31 - m : m;
    const int qrow = qbi * 64 + wave * 16;
    const int qg = qrow + lm;
    const int nt = qbi + 1;

    const ushort* qp = QKV + qcol + (size_t)(qrow + lm) * LD;
    short8 qa0 = *(const short8*)(qp + quad * 8);
    short8 qa1 = *(const short8*)(qp + 32 + quad * 8);

    f32x4 accz[4] = {};   // Z C-layout: row q=quad*4+r, col h=c*16+lm
    f32x4 lacc = {};      // row-sum via ones-MFMA: l for q=quad*4+r in lacc[r]

    block_sync_lds();  // prior pass's vt/kt reads complete before restage

    // K tile 0 -> kt[0] (direct-to-LDS), V tile 0 -> vt[0] (reg-staged)
    stage_k(kglob, 0, kt[0], wave, lane);
#pragma unroll
    for (int rr = 0; rr < 2; ++rr) {
      const int p = plb + rr * 32;
      short8 v = *(const short8*)(QKV + vcol + (size_t)p * LD + h0);
      vt_write8(vt[0], h0, hsw, p, v);
    }

    for (int it = 0; it < nt; ++it) {
      const int p0 = it * 64;
      // kt/vt of this iter visible. Only well-aged stage loads drained.
      block_sync_full();

      // K fragments from LDS (block-shared; swizzled chunks, conflict-free)
      short8 ka[4], kb[4];
      const ushort* kbuf = kt[it & 1];
#pragma unroll
      for (int s = 0; s < 4; ++s) {
        const ushort* kr = kbuf + (s * 16 + lm) * 64;
        ka[s] = *(const short8*)(kr + (((quad ^ ksw) & 7) << 3));
        kb[s] = *(const short8*)(kr + ((((quad + 4) ^ ksw) & 7) << 3));
      }

      const bool more = (it + 1 < nt);
      // early global V load for it+1 (LDS write deferred to end of iter)
      short8 nv0, nv1;
      if (more) {
        nv0 = *(const short8*)(QKV + vcol + (size_t)(p0 + 64 + plb) * LD + h0);
        nv1 = *(const short8*)(QKV + vcol + (size_t)(p0 + 96 + plb) * LD + h0);
        // stage K for it+1 into the other buffer (issued AFTER nv: the nv
        // wait at vt_write8 is then vmcnt(2), leaving these in flight)
        stage_k(kglob, p0 + 64, kt[(it + 1) & 1], wave, lane);
      }

      // scores S^T[p][q] (8 MFMA)
      f32x4 t4[4];
      __builtin_amdgcn_s_setprio(1);
#pragma unroll
      for (int s = 0; s < 4; ++s) {
        f32x4 t = {0.f, 0.f, 0.f, 0.f};
        t = MFMA16(ka[s], qa0, t);
        t = MFMA16(kb[s], qa1, t);
        t4[s] = t;
      }
      __builtin_amdgcn_s_setprio(0);

      // fixed-shift softmax: p = exp2(S*log2e/8); mask only on diagonal tile
      float ps[4][4];
      if (it != nt - 1) {
#pragma unroll
        for (int s = 0; s < 4; ++s)
#pragma unroll
          for (int r = 0; r < 4; ++r)
            ps[s][r] = fexp2(t4[s][r] * CSC);
      } else {
#pragma unroll
        for (int s = 0; s < 4; ++s)
#pragma unroll
          for (int r = 0; r < 4; ++r) {
            const int pg = p0 + s * 16 + quad * 4 + r;
            const float e = fexp2(t4[s][r] * CSC);
            ps[s][r] = (pg > qg) ? 0.f : e;
          }
      }

      // pack P^T (C-layout) -> per-wave LDS (same-wave, no barrier).
      ushort* pw = pbuf[wave] + lm * 64;
#pragma unroll
      for (int s = 0; s < 4; ++s) {
        uint2 pk;
        pk.x = (uint)f2bf(ps[s][0]) | ((uint)f2bf(ps[s][1]) << 16);
        pk.y = (uint)f2bf(ps[s][2]) | ((uint)f2bf(ps[s][3]) << 16);
        *(uint2*)(pw + ((((2 * s + (quad >> 1)) ^ psw) & 7) << 3) +
                  ((quad & 1) << 2)) = pk;
      }

      // PV: accz[q][h] += P[q][p] * V[p][h]; lacc[q] += P[q][p] * 1
      const ushort* vbuf = vt[it & 1];
      __builtin_amdgcn_s_setprio(1);
#pragma unroll
      for (int kc = 0; kc < 2; ++kc) {
        short8 pa = *(const short8*)(pw + ((((kc * 4 + quad) ^ psw) & 7) << 3));
        lacc = MFMA16(pa, vone, lacc);
#pragma unroll
        for (int c = 0; c < 4; ++c) {
          const int hrow = c * 16 + lm;
          const int fh = ((hrow >> 3) ^ hrow) & 7;
          short8 vb = *(const short8*)(
              vbuf + hrow * 64 + ((((4 * kc + quad) ^ fh) & 7) << 3));
          accz[c] = MFMA16(pa, vb, accz[c]);
        }
      }
      __builtin_amdgcn_s_setprio(0);

      // late LDS writes of next V tile; compiler waits vmcnt(2) for nv0/nv1
      // (stage_k loads stay outstanding until next barrier)
      if (more) {
        ushort* nbuf = vt[(it + 1) & 1];
        vt_write8(nbuf, h0, hsw, plb, nv0);
        vt_write8(nbuf, h0, hsw, plb + 32, nv1);
      }
    }

    // epilogue: lacc[r] holds the full row-sum for q=quad*4+r (uniform over
    // lm since all ones-B columns are equal) -> scale + write Z over Q.
#pragma unroll
    for (int r = 0; r < 4; ++r) {
      const float inv = 1.f / lacc[r];
#pragma unroll
      for (int c = 0; c < 4; ++c)
        QKV[qcol + (size_t)(qrow + quad * 4 + r) * LD + c * 16 + lm] =
            f2bf(accz[c][r] * inv);
    }
  }
}

extern "C" void kernel_launch(void* const* d_in, const int* in_sizes, int n_in,
                              void* d_out, int out_size, void* d_ws, size_t ws_size,
                              hipStream_t stream) {
  (void)in_sizes; (void)n_in; (void)out_size; (void)ws_size;
  const float* x  = (const float*)d_in[0];   // (4,2048,1024) = (8192,1024)
  const float* wk = (const float*)d_in[1];   // (16,64,1024) flat (1024,1024)
  const float* wq = (const float*)d_in[2];
  const float* wv = (const float*)d_in[3];
  const float* wo = (const float*)d_in[4];   // (1024,1024)
  float* out = (float*)d_out;

  const size_t WSZ = (size_t)1024 * 1024;
  ushort* wqkv_b = (ushort*)d_ws;            // rows: 0..1023 Q, 1024.. K, 2048.. V
  ushort* wo_b = wqkv_b + 3 * WSZ;
  ushort* QKV = wo_b + WSZ;                  // 8192 x 3072
  ushort* xb = (ushort*)d_out;               // bf16 x in d_out (16 of 32 MB);
                                             // dead before out-proj writes

  // Fused converts: 4*(1M/4) + (8M/4) = 3145728 float4s = 12288 blocks exact.
  convert_all_kernel<<<12288, 256, 0, stream>>>(wq, wk, wv, wo, x,
                                                wqkv_b, wo_b, xb);

  // All-batch QKV projection. Grid 24 N-tiles x 64 M-tiles = 1536 blocks;
  // XCD remap cpx=3: each XCD's 768 KB B sub-panel stays L2-resident.
  gemm_kernel<__hip_bfloat16><<<1536, 256, 0, stream>>>(
      xb, 1024, wqkv_b, 1024, (__hip_bfloat16*)QKV, 3072, 1024, 3);

  flash4_kernel<<<1024, 256, 0, stream>>>(QKV);

  // Out projection: Z (QKV cols 0..1023) * Wo^T -> fp32 out.
  gemm_kernel<float><<<512, 256, 0, stream>>>(
      QKV, 3072, wo_b, 1024, out, 1024, 1024, 1);
}

// Round 7
// 251.026 us; speedup vs baseline: 1.0993x; 1.0542x over previous
//
#include <hip/hip_runtime.h>
#include <hip/hip_bf16.h>

// Attention forward, MI355X (gfx950). fp32 in/out, bf16 MFMA internally.
// ws (56 MB): wqkv_b[3072x1024 bf16] | wo_b[1024x1024 bf16] | QKV[8192x3072 bf16]
// xb (bf16 x) lives in d_out's first 16 MB (dead before out-proj writes).
// Dispatches: 1 fused convert; QKV GEMM (3-buf pipelined); flash; out-proj GEMM.
// MFMA layouts (verified m89/m74):
//   A-frag: A[m=lane&15][k=(lane>>4)*8+j]; B-frag: B[n=lane&15][k=...]
//   C/D:    col=lane&15, row=(lane>>4)*4+reg
//
// Round-8:  both-sides LDS swizzles in flash. Conflicts 1.62e7->6.5e6, dur flat.
// Round-9:  lgkm-only barrier in flash. 163->157 us.
// Round-10: K LDS-staged (pre-swizzled source) + XCD grouping in flash.
//           FETCH 240->38 MB, flash 157->89.6 us. Latency theory confirmed.
// Round-11: GEMM XCD remap + BK=64 swizzled staging + fused converts. 280->262.
// Round-12: fused pair p-loop: np non-uniform per CU -> 105 us. REVERTED.
// Round-13: revert + ones-MFMA l-sum + setprio: flash 86.3 us, VGPR 84.
// Round-14 (this): QKV GEMM -> gemm3: 128Mx256N tile, BK=64, 8 waves, THREE
//   LDS buffers (144 KB) = depth-2 prefetch with NO overwrite-while-read by
//   construction (stage t+2 hits the buffer last read in group t-1).
//   Counted vmcnt(6) at group boundaries only (T4), 2 phases/tile of
//   {12/4 ds_read | stage | barrier | lgkm0 | setprio+16 MFMA | barrier}
//   (T3), both-sides XOR swizzle (T2), setprio (T5), XCD M-ownership (T1).
//   Out-proj & flash untouched for attribution.

typedef short short8 __attribute__((ext_vector_type(8)));
typedef float f32x4 __attribute__((ext_vector_type(4)));

#define MFMA16(a, b, c) __builtin_amdgcn_mfma_f32_16x16x32_bf16((a), (b), (c), 0, 0, 0)

static __device__ __forceinline__ ushort f2bf(float f) {
  union { __hip_bfloat16 h; ushort u; } cv;
  cv.h = __float2bfloat16(f);
  return cv.u;
}

static __device__ __forceinline__ float fexp2(float x) {
#if __has_builtin(__builtin_amdgcn_exp2f)
  return __builtin_amdgcn_exp2f(x);
#else
  return __expf(x * 0.69314718056f);
#endif
}

// Barrier WITHOUT any vmcnt drain: LDS writes visible, globals keep flying.
static __device__ __forceinline__ void block_sync_lds() {
  asm volatile("s_waitcnt lgkmcnt(0)" ::: "memory");
  __builtin_amdgcn_s_barrier();
  __builtin_amdgcn_sched_barrier(0);
}

// Barrier that ALSO waits outstanding globals (global_load_lds visibility).
static __device__ __forceinline__ void block_sync_full() {
  asm volatile("s_waitcnt vmcnt(0) lgkmcnt(0)" ::: "memory");
  __builtin_amdgcn_s_barrier();
  __builtin_amdgcn_sched_barrier(0);
}

static __device__ __forceinline__ void store_out(float* p, float v) { *p = v; }
static __device__ __forceinline__ void store_out(__hip_bfloat16* p, float v) {
  *p = __float2bfloat16(v);
}

// One fused convert: wq|wk|wv -> wqkv_b rows, wo -> wo_b, x -> xb.
__global__ __launch_bounds__(256) void convert_all_kernel(
    const float* __restrict__ wq, const float* __restrict__ wk,
    const float* __restrict__ wv, const float* __restrict__ wo,
    const float* __restrict__ x, ushort* __restrict__ wqkv,
    ushort* __restrict__ wob, ushort* __restrict__ xb) {
  constexpr int W4 = 262144;           // (1024*1024)/4
  constexpr size_t WSZ = (size_t)1024 * 1024;
  const int i = blockIdx.x * blockDim.x + threadIdx.x;
  const float* src;
  ushort* dst;
  int j;
  if (i < 2 * W4) {
    if (i < W4)      { src = wq; dst = wqkv;           j = i; }
    else             { src = wk; dst = wqkv + WSZ;     j = i - W4; }
  } else if (i < 4 * W4) {
    if (i < 3 * W4)  { src = wv; dst = wqkv + 2 * WSZ; j = i - 2 * W4; }
    else             { src = wo; dst = wob;            j = i - 3 * W4; }
  } else {
    src = x; dst = xb; j = i - 4 * W4;
  }
  const float4 v = ((const float4*)src)[j];
  ushort4 o;
  o.x = f2bf(v.x); o.y = f2bf(v.y); o.z = f2bf(v.z); o.w = f2bf(v.w);
  ((ushort4*)dst)[j] = o;
}

// ---------------- old 128x128 GEMM (kept for out-proj) ----------------
// C[M,N] = A[M,K](bf16) * B[N,K]^T(bf16), fp32 acc. BK=64, pre-swizzled
// global_load_lds staging, conflict-free ds_read_b128. 4 waves, 64x64/wave.
template <typename OUT_T>
__global__ __launch_bounds__(256) void gemm_kernel(
    const ushort* __restrict__ A, int lda, const ushort* __restrict__ B, int ldb,
    OUT_T* __restrict__ C, int ldc, int K, int cpx) {
  __shared__ __align__(16) ushort As[128 * 64];
  __shared__ __align__(16) ushort Bs[128 * 64];
  const int tid = threadIdx.x;
  const int wave = tid >> 6, lane = tid & 63;
  const int lm = lane & 15, quad = lane >> 4;

  const int id = blockIdx.x;
  const int local = id >> 3;
  const int nt = (id & 7) * cpx + local % cpx;
  const int mt = local / cpx;
  const size_t m0 = (size_t)mt * 128;
  const size_t n0 = (size_t)nt * 128;

  const int rl = lane >> 3;        // row within 8-row staging chunk
  const int cs = (lane & 7) ^ rl;  // pre-swizzled source col-chunk
  const int fsw = lm & 7;          // fragment read swizzle key

  f32x4 acc[4][4] = {};
  for (int k0 = 0; k0 < K; k0 += 64) {
    __syncthreads();
#pragma unroll
    for (int j = 0; j < 4; ++j) {
      const int ch = wave * 4 + j;  // 8-row chunk 0..15
      const ushort* gb = B + (n0 + ch * 8 + rl) * (size_t)ldb + k0 + cs * 8;
      __builtin_amdgcn_global_load_lds(
          (const __attribute__((address_space(1))) void*)gb,
          (__attribute__((address_space(3))) void*)(Bs + ch * 512), 16, 0, 0);
      const ushort* ga = A + (m0 + ch * 8 + rl) * (size_t)lda + k0 + cs * 8;
      __builtin_amdgcn_global_load_lds(
          (const __attribute__((address_space(1))) void*)ga,
          (__attribute__((address_space(3))) void*)(As + ch * 512), 16, 0, 0);
    }
    __syncthreads();  // vmcnt drain required: staging must be visible

    const int wm = (wave >> 1) * 64, wn = (wave & 1) * 64;
#pragma unroll
    for (int ks = 0; ks < 2; ++ks) {
      short8 a[4], b[4];
#pragma unroll
      for (int i = 0; i < 4; ++i)
        a[i] = *(const short8*)(As + (wm + i * 16 + lm) * 64 +
                                ((((ks * 4 + quad) ^ fsw) & 7) << 3));
#pragma unroll
      for (int j = 0; j < 4; ++j)
        b[j] = *(const short8*)(Bs + (wn + j * 16 + lm) * 64 +
                                ((((ks * 4 + quad) ^ fsw) & 7) << 3));
#pragma unroll
      for (int i = 0; i < 4; ++i)
#pragma unroll
        for (int j = 0; j < 4; ++j)
          acc[i][j] = MFMA16(a[i], b[j], acc[i][j]);
    }
  }

  const int wm = (wave >> 1) * 64, wn = (wave & 1) * 64;
  const int rq = quad * 4;
#pragma unroll
  for (int i = 0; i < 4; ++i)
#pragma unroll
    for (int j = 0; j < 4; ++j)
#pragma unroll
      for (int r = 0; r < 4; ++r)
        store_out(&C[(m0 + wm + i * 16 + rq + r) * (size_t)ldc + n0 + wn + j * 16 + lm],
                  acc[i][j][r]);
}

// ---------------- new 128M x 256N 3-buffer pipelined GEMM ----------------
// Stage one part of K-tile k0 into (abuf,bbuf): part0 = A rows 0..127 (2
// loads) + B rows 0..127 (2); part1 = B rows 128..255 (2). Pre-swizzled
// source (rule 21): element (r, chunk c) lands at phys chunk c^(r&7).
static __device__ __forceinline__ void stage_part(
    const ushort* __restrict__ Ab, int lda, const ushort* __restrict__ Bb,
    int ldb, int k0, ushort* abuf, ushort* bbuf, int wave, int lane, int part) {
  const int rl = lane >> 3, c8 = lane & 7;
  const int cs = c8 ^ rl;  // r&7 == rl for all rows below
  if (part == 0) {
#pragma unroll
    for (int i = 0; i < 2; ++i) {
      const int r = i * 64 + wave * 8 + rl;
      __builtin_amdgcn_global_load_lds(
          (const __attribute__((address_space(1))) void*)(Ab + (size_t)r * lda + k0 + cs * 8),
          (__attribute__((address_space(3))) void*)(abuf + (i * 8 + wave) * 512), 16, 0, 0);
    }
#pragma unroll
    for (int i = 0; i < 2; ++i) {
      const int r = i * 64 + wave * 8 + rl;
      __builtin_amdgcn_global_load_lds(
          (const __attribute__((address_space(1))) void*)(Bb + (size_t)r * ldb + k0 + cs * 8),
          (__attribute__((address_space(3))) void*)(bbuf + (i * 8 + wave) * 512), 16, 0, 0);
    }
  } else {
#pragma unroll
    for (int i = 2; i < 4; ++i) {
      const int r = i * 64 + wave * 8 + rl;
      __builtin_amdgcn_global_load_lds(
          (const __attribute__((address_space(1))) void*)(Bb + (size_t)r * ldb + k0 + cs * 8),
          (__attribute__((address_space(3))) void*)(bbuf + (i * 8 + wave) * 512), 16, 0, 0);
    }
  }
}

// C[M,N] = A[M,K] * B[N,K]^T, bf16 in, OUT_T out. 512 threads = 8 waves
// (2M x 4N), wave tile 64x64 (4x4 frags). 3 LDS buffers: while group t
// computes buf t%3, tile t+2 stages into buf (t+2)%3 (last read in group
// t-1; all waves past that group's exit barrier) -> NO overwrite race.
// Group boundary waits vmcnt(6) (the 6 t+2 loads) so tile t+1 is landed;
// never vmcnt(0) mid-loop (T4). 2 phases/tile: ph0 reads B[4][2]+A mf01 and
// computes mf01; ph1 reads A mf23 (B reused in regs) and computes mf23.
// Grid 768 = 8 XCD x 8 mt x 12 nt: xcd=id&7 owns mt = xcd*8 + (local&7),
// nt = local>>3 -> consecutive blocks share a B N-panel; XCD's 8 A-panels
// (2 MB) stay L2-resident.
template <typename OUT_T>
__global__ __launch_bounds__(512, 2) void gemm3_kernel(
    const ushort* __restrict__ A, int lda, const ushort* __restrict__ B, int ldb,
    OUT_T* __restrict__ C, int ldc, int K) {
  __shared__ __align__(16) ushort As[3][128 * 64];
  __shared__ __align__(16) ushort Bs[3][256 * 64];

  const int tid = threadIdx.x;
  const int wave = tid >> 6, lane = tid & 63;
  const int lm = lane & 15, quad = lane >> 4;
  const int wm = wave >> 2, wn = wave & 3;

  const int id = blockIdx.x;
  const int mt = (id & 7) * 8 + ((id >> 3) & 7);
  const int nt = id >> 6;
  const size_t m0 = (size_t)mt * 128;
  const size_t n0 = (size_t)nt * 256;

  const ushort* Abase = A + m0 * (size_t)lda;
  const ushort* Bbase = B + n0 * (size_t)ldb;
  const int fsw = lm & 7;
  const int T = K >> 6;

  // prologue: stage tiles 0 and 1 (12 loads), wait tile 0 (6 newest flying)
  stage_part(Abase, lda, Bbase, ldb, 0, As[0], Bs[0], wave, lane, 0);
  stage_part(Abase, lda, Bbase, ldb, 0, As[0], Bs[0], wave, lane, 1);
  stage_part(Abase, lda, Bbase, ldb, 64, As[1], Bs[1], wave, lane, 0);
  stage_part(Abase, lda, Bbase, ldb, 64, As[1], Bs[1], wave, lane, 1);
  asm volatile("s_waitcnt vmcnt(6)" ::: "memory");
  __builtin_amdgcn_s_barrier();
  __builtin_amdgcn_sched_barrier(0);

  f32x4 acc[4][4] = {};
  int bt = 0, bs = 2;  // buf of tile t / of tile t+2
  for (int t = 0; t < T; ++t) {
    const ushort* ab = As[bt];
    const ushort* bb = Bs[bt];
    const bool pre = (t + 2 < T);
    const int kp = (t + 2) << 6;

    // ---- phase 0: B all frags + A mf 0,1; MFMA mf 0,1 ----
    short8 bfr[4][2], a0[2][2];
#pragma unroll
    for (int nf = 0; nf < 4; ++nf) {
      const ushort* br = bb + (wn * 64 + nf * 16 + lm) * 64;
#pragma unroll
      for (int ks = 0; ks < 2; ++ks)
        bfr[nf][ks] = *(const short8*)(br + ((((ks * 4 + quad) ^ fsw) & 7) << 3));
    }
#pragma unroll
    for (int mf = 0; mf < 2; ++mf) {
      const ushort* ar = ab + (wm * 64 + mf * 16 + lm) * 64;
#pragma unroll
      for (int ks = 0; ks < 2; ++ks)
        a0[mf][ks] = *(const short8*)(ar + ((((ks * 4 + quad) ^ fsw) & 7) << 3));
    }
    if (pre) stage_part(Abase, lda, Bbase, ldb, kp, As[bs], Bs[bs], wave, lane, 0);
    asm volatile("" ::: "memory");
    __builtin_amdgcn_s_barrier();
    asm volatile("s_waitcnt lgkmcnt(0)" ::: "memory");
    __builtin_amdgcn_sched_barrier(0);
    __builtin_amdgcn_s_setprio(1);
#pragma unroll
    for (int mf = 0; mf < 2; ++mf)
#pragma unroll
      for (int nf = 0; nf < 4; ++nf)
#pragma unroll
        for (int ks = 0; ks < 2; ++ks)
          acc[mf][nf] = MFMA16(a0[mf][ks], bfr[nf][ks], acc[mf][nf]);
    __builtin_amdgcn_s_setprio(0);
    asm volatile("" ::: "memory");
    __builtin_amdgcn_s_barrier();

    // ---- phase 1: A mf 2,3; MFMA mf 2,3 (B reused from regs) ----
    short8 a1[2][2];
#pragma unroll
    for (int mf = 0; mf < 2; ++mf) {
      const ushort* ar = ab + (wm * 64 + (mf + 2) * 16 + lm) * 64;
#pragma unroll
      for (int ks = 0; ks < 2; ++ks)
        a1[mf][ks] = *(const short8*)(ar + ((((ks * 4 + quad) ^ fsw) & 7) << 3));
    }
    if (pre) stage_part(Abase, lda, Bbase, ldb, kp, As[bs], Bs[bs], wave, lane, 1);
    // group boundary: ensure tile t+1 landed; keep t+2's 6 loads flying
    if (pre) asm volatile("s_waitcnt vmcnt(6)" ::: "memory");
    else     asm volatile("s_waitcnt vmcnt(0)" ::: "memory");
    __builtin_amdgcn_s_barrier();
    asm volatile("s_waitcnt lgkmcnt(0)" ::: "memory");
    __builtin_amdgcn_sched_barrier(0);
    __builtin_amdgcn_s_setprio(1);
#pragma unroll
    for (int mf = 0; mf < 2; ++mf)
#pragma unroll
      for (int nf = 0; nf < 4; ++nf)
#pragma unroll
        for (int ks = 0; ks < 2; ++ks)
          acc[mf + 2][nf] = MFMA16(a1[mf][ks], bfr[nf][ks], acc[mf + 2][nf]);
    __builtin_amdgcn_s_setprio(0);
    asm volatile("" ::: "memory");
    __builtin_amdgcn_s_barrier();

    bt = (bt == 2) ? 0 : bt + 1;
    bs = (bs == 2) ? 0 : bs + 1;
  }

  // epilogue: C write, same C/D mapping as gemm_kernel
#pragma unroll
  for (int mf = 0; mf < 4; ++mf)
#pragma unroll
    for (int nf = 0; nf < 4; ++nf)
#pragma unroll
      for (int r = 0; r < 4; ++r)
        store_out(&C[(m0 + wm * 64 + mf * 16 + quad * 4 + r) * (size_t)ldc +
                     n0 + wn * 64 + nf * 16 + lm],
                  acc[mf][nf][r]);
}

// Swizzled V^T LDS write: 8 cols starting at h0 for row p.
// Element (p, h) lives at h*64 + (((p>>3) ^ (h>>3) ^ (h&7)) & 7)*8 + (p&7).
static __device__ __forceinline__ void vt_write8(ushort* vtbuf, int h0, int hsw,
                                                 int p, const short8& v) {
  const int pc = (p >> 3) ^ hsw;
  ushort* row = vtbuf + h0 * 64 + (p & 7);
#pragma unroll
  for (int u = 0; u < 8; ++u)
    row[u * 64 + (((pc ^ u) & 7) << 3)] = ((const ushort*)&v)[u];
}

// Stage a 64x64 bf16 K tile (global rows pbase..pbase+63) into kbuf via
// global_load_lds, pre-swizzled source (rule 21).
static __device__ __forceinline__ void stage_k(const ushort* kglob, int pbase,
                                               ushort* kbuf, int wave, int lane) {
  const int rl = lane >> 3;           // row within the 8-row chunk (== r&7)
  const int c = (lane & 7) ^ rl;      // inverse-swizzled source chunk
#pragma unroll
  for (int j = 0; j < 2; ++j) {
    const int ch = wave * 2 + j;
    const ushort* src = kglob + (size_t)(pbase + ch * 8 + rl) * 3072 + c * 8;
    __builtin_amdgcn_global_load_lds(
        (const __attribute__((address_space(1))) void*)src,
        (__attribute__((address_space(3))) void*)(kbuf + ch * 512), 16, 0, 0);
  }
}

// Flash causal attention (round-4 structure + round-13 micros; verified 86.3).
__global__ __launch_bounds__(256) void flash4_kernel(ushort* __restrict__ QKV) {
  constexpr int LD = 3072;
  __shared__ __align__(16) ushort vt[2][64 * 64];
  __shared__ __align__(16) ushort kt[2][64 * 64];
  __shared__ __align__(16) ushort pbuf[4][16 * 64];

  const int id = blockIdx.x;
  const int g = (id & 7) * 8 + ((id >> 3) & 7);  // (b,head) group, XCD-local
  const int m = id >> 6;                          // q-pair index 0..15
  const int head = g & 15;
  const int b = g >> 4;

  const int tid = threadIdx.x;
  const int wave = tid >> 6, lane = tid & 63;
  const int lm = lane & 15, quad = lane >> 4;

  const size_t qcol = (size_t)b * 2048 * LD + head * 64;
  const size_t vcol = qcol + 2048;
  const ushort* kglob = QKV + qcol + 1024;

  const int h0 = (tid & 7) * 8;  // V staging: 8 cols per thread
  const int hsw = tid & 7;
  const int plb = tid >> 3;      // V staging p base (0..31)
  const int psw = lm & 7;        // pbuf row swizzle key
  const int ksw = lm & 7;        // kt fragment swizzle key

  constexpr float CSC = 0.180336880f;  // log2(e)/8
  const short8 vone = {0x3F80, 0x3F80, 0x3F80, 0x3F80,
                       0x3F80, 0x3F80, 0x3F80, 0x3F80};  // bf16 1.0 x8

  for (int pass = 0; pass < 2; ++pass) {
    const int qbi = pass ? 31 - m : m;
    const int qrow = qbi * 64 + wave * 16;
    const int qg = qrow + lm;
    const int nt = qbi + 1;

    const ushort* qp = QKV + qcol + (size_t)(qrow + lm) * LD;
    short8 qa0 = *(const short8*)(qp + quad * 8);
    short8 qa1 = *(const short8*)(qp + 32 + quad * 8);

    f32x4 accz[4] = {};   // Z C-layout: row q=quad*4+r, col h=c*16+lm
    f32x4 lacc = {};      // row-sum via ones-MFMA

    block_sync_lds();  // prior pass's vt/kt reads complete before restage

    stage_k(kglob, 0, kt[0], wave, lane);
#pragma unroll
    for (int rr = 0; rr < 2; ++rr) {
      const int p = plb + rr * 32;
      short8 v = *(const short8*)(QKV + vcol + (size_t)p * LD + h0);
      vt_write8(vt[0], h0, hsw, p, v);
    }

    for (int it = 0; it < nt; ++it) {
      const int p0 = it * 64;
      block_sync_full();

      short8 ka[4], kb[4];
      const ushort* kbuf = kt[it & 1];
#pragma unroll
      for (int s = 0; s < 4; ++s) {
        const ushort* kr = kbuf + (s * 16 + lm) * 64;
        ka[s] = *(const short8*)(kr + (((quad ^ ksw) & 7) << 3));
        kb[s] = *(const short8*)(kr + ((((quad + 4) ^ ksw) & 7) << 3));
      }

      const bool more = (it + 1 < nt);
      short8 nv0, nv1;
      if (more) {
        nv0 = *(const short8*)(QKV + vcol + (size_t)(p0 + 64 + plb) * LD + h0);
        nv1 = *(const short8*)(QKV + vcol + (size_t)(p0 + 96 + plb) * LD + h0);
        stage_k(kglob, p0 + 64, kt[(it + 1) & 1], wave, lane);
      }

      f32x4 t4[4];
      __builtin_amdgcn_s_setprio(1);
#pragma unroll
      for (int s = 0; s < 4; ++s) {
        f32x4 t = {0.f, 0.f, 0.f, 0.f};
        t = MFMA16(ka[s], qa0, t);
        t = MFMA16(kb[s], qa1, t);
        t4[s] = t;
      }
      __builtin_amdgcn_s_setprio(0);

      float ps[4][4];
      if (it != nt - 1) {
#pragma unroll
        for (int s = 0; s < 4; ++s)
#pragma unroll
          for (int r = 0; r < 4; ++r)
            ps[s][r] = fexp2(t4[s][r] * CSC);
      } else {
#pragma unroll
        for (int s = 0; s < 4; ++s)
#pragma unroll
          for (int r = 0; r < 4; ++r) {
            const int pg = p0 + s * 16 + quad * 4 + r;
            const float e = fexp2(t4[s][r] * CSC);
            ps[s][r] = (pg > qg) ? 0.f : e;
          }
      }

      ushort* pw = pbuf[wave] + lm * 64;
#pragma unroll
      for (int s = 0; s < 4; ++s) {
        uint2 pk;
        pk.x = (uint)f2bf(ps[s][0]) | ((uint)f2bf(ps[s][1]) << 16);
        pk.y = (uint)f2bf(ps[s][2]) | ((uint)f2bf(ps[s][3]) << 16);
        *(uint2*)(pw + ((((2 * s + (quad >> 1)) ^ psw) & 7) << 3) +
                  ((quad & 1) << 2)) = pk;
      }

      const ushort* vbuf = vt[it & 1];
      __builtin_amdgcn_s_setprio(1);
#pragma unroll
      for (int kc = 0; kc < 2; ++kc) {
        short8 pa = *(const short8*)(pw + ((((kc * 4 + quad) ^ psw) & 7) << 3));
        lacc = MFMA16(pa, vone, lacc);
#pragma unroll
        for (int c = 0; c < 4; ++c) {
          const int hrow = c * 16 + lm;
          const int fh = ((hrow >> 3) ^ hrow) & 7;
          short8 vb = *(const short8*)(
              vbuf + hrow * 64 + ((((4 * kc + quad) ^ fh) & 7) << 3));
          accz[c] = MFMA16(pa, vb, accz[c]);
        }
      }
      __builtin_amdgcn_s_setprio(0);

      if (more) {
        ushort* nbuf = vt[(it + 1) & 1];
        vt_write8(nbuf, h0, hsw, plb, nv0);
        vt_write8(nbuf, h0, hsw, plb + 32, nv1);
      }
    }

#pragma unroll
    for (int r = 0; r < 4; ++r) {
      const float inv = 1.f / lacc[r];
#pragma unroll
      for (int c = 0; c < 4; ++c)
        QKV[qcol + (size_t)(qrow + quad * 4 + r) * LD + c * 16 + lm] =
            f2bf(accz[c][r] * inv);
    }
  }
}

extern "C" void kernel_launch(void* const* d_in, const int* in_sizes, int n_in,
                              void* d_out, int out_size, void* d_ws, size_t ws_size,
                              hipStream_t stream) {
  (void)in_sizes; (void)n_in; (void)out_size; (void)ws_size;
  const float* x  = (const float*)d_in[0];   // (4,2048,1024) = (8192,1024)
  const float* wk = (const float*)d_in[1];   // (16,64,1024) flat (1024,1024)
  const float* wq = (const float*)d_in[2];
  const float* wv = (const float*)d_in[3];
  const float* wo = (const float*)d_in[4];   // (1024,1024)
  float* out = (float*)d_out;

  const size_t WSZ = (size_t)1024 * 1024;
  ushort* wqkv_b = (ushort*)d_ws;            // rows: 0..1023 Q, 1024.. K, 2048.. V
  ushort* wo_b = wqkv_b + 3 * WSZ;
  ushort* QKV = wo_b + WSZ;                  // 8192 x 3072
  ushort* xb = (ushort*)d_out;               // bf16 x in d_out (16 of 32 MB);
                                             // dead before out-proj writes

  // Fused converts: 4*(1M/4) + (8M/4) = 3145728 float4s = 12288 blocks exact.
  convert_all_kernel<<<12288, 256, 0, stream>>>(wq, wk, wv, wo, x,
                                                wqkv_b, wo_b, xb);

  // All-batch QKV projection: 3-buffer pipelined 128x256 tiles.
  // Grid 768 = 8 XCD x 8 M-tiles x 12 N-tiles, 512 threads, 144 KB LDS.
  gemm3_kernel<__hip_bfloat16><<<768, 512, 0, stream>>>(
      xb, 1024, wqkv_b, 1024, (__hip_bfloat16*)QKV, 3072, 1024);

  flash4_kernel<<<1024, 256, 0, stream>>>(QKV);

  // Out projection: Z (QKV cols 0..1023) * Wo^T -> fp32 out (old kernel).
  gemm_kernel<float><<<512, 256, 0, stream>>>(
      QKV, 3072, wo_b, 1024, out, 1024, 1024, 1);
}